// Round 1
// baseline (1349.671 us; speedup 1.0000x reference)
//
#include <hip/hip_runtime.h>
#include <cstddef>

#define TT 256
#define HH 128
#define ENC_STRIDE 132   // +4 pad: bank-quad (t+c)&7 spread for strided float4 reads

struct __align__(16) SM {
  float enc[TT * ENC_STRIDE];   // 135168 B: enc_proj[b], padded rows
  float xloc[TT * 2];           // 2048 B
  float h[HH];                  // 512 B
  float uc2[HH];                // 512 B : (h@W2)*2log2e
  float v2[HH];                 // 512 B : -2*V
  float red_s[8];
  int   red_t[8];
  float sv;                     // sum(V)
};

__device__ __forceinline__ float fast_sigmoid(float x) {
  const float L2E = 1.4426950408889634f;
  float y = __builtin_amdgcn_exp2f(-x * L2E);
  return __builtin_amdgcn_rcpf(1.0f + y);
}
__device__ __forceinline__ float fast_tanh(float x) {
  const float C2 = 2.8853900817779268f;   // 2*log2(e)
  float y = __builtin_amdgcn_exp2f(x * C2);
  return 1.0f - 2.0f * __builtin_amdgcn_rcpf(1.0f + y);
}

// One workgroup per batch element; 512 threads = 8 waves; all 256 steps in-kernel.
__global__ __launch_bounds__(512, 2)
void decoder_kernel(const float* __restrict__ x,
                    const float* __restrict__ enc_output,
                    const float* __restrict__ h0,
                    const float* __restrict__ c0,
                    const float* __restrict__ W1,
                    const float* __restrict__ W2,
                    const float* __restrict__ V,
                    const float* __restrict__ Wk,
                    const float* __restrict__ Wr,
                    const float* __restrict__ bias,
                    float* __restrict__ out)
{
  __shared__ SM sm;
  const int u = threadIdx.x;
  const int b = blockIdx.x;

  // ---------------- prologue ----------------
  sm.xloc[u] = x[b * (TT * 2) + u];
  if (u < HH) {
    sm.h[u]  = h0[b * HH + u];
    sm.v2[u] = -2.0f * V[u];
  }
  if (u < 64) {
    float v = V[u] + V[u + 64];
    #pragma unroll
    for (int o = 1; o < 64; o <<= 1) v += __shfl_xor(v, o, 64);
    if (u == 0) sm.sv = v;
  }

  // enc_proj = enc_output[b] @ W1 -> sm.enc (padded). Thread u: row t=p*32+(u>>4),
  // cols ks..ks+7 with ks=(u&15)*8. enc row shared by 16 lanes (L1 broadcast),
  // W1 float4 loads shared across tsub groups (L1/L2 cached).
  {
    const float* encb = enc_output + (size_t)b * TT * HH;
    const int tsub = u >> 4;
    const int ks   = (u & 15) * 8;
    for (int p = 0; p < 8; ++p) {
      const int t = p * 32 + tsub;
      float4 a0 = {0.f, 0.f, 0.f, 0.f};
      float4 a1 = {0.f, 0.f, 0.f, 0.f};
      const float4* er4 = (const float4*)(encb + t * HH);
      for (int j4 = 0; j4 < 32; ++j4) {
        const float4 ev = er4[j4];
        const float* w1p = W1 + (j4 * 4) * HH + ks;
        float4 wa, wb;
        wa = *(const float4*)(w1p + 0 * HH); wb = *(const float4*)(w1p + 0 * HH + 4);
        a0.x += ev.x * wa.x; a0.y += ev.x * wa.y; a0.z += ev.x * wa.z; a0.w += ev.x * wa.w;
        a1.x += ev.x * wb.x; a1.y += ev.x * wb.y; a1.z += ev.x * wb.z; a1.w += ev.x * wb.w;
        wa = *(const float4*)(w1p + 1 * HH); wb = *(const float4*)(w1p + 1 * HH + 4);
        a0.x += ev.y * wa.x; a0.y += ev.y * wa.y; a0.z += ev.y * wa.z; a0.w += ev.y * wa.w;
        a1.x += ev.y * wb.x; a1.y += ev.y * wb.y; a1.z += ev.y * wb.z; a1.w += ev.y * wb.w;
        wa = *(const float4*)(w1p + 2 * HH); wb = *(const float4*)(w1p + 2 * HH + 4);
        a0.x += ev.z * wa.x; a0.y += ev.z * wa.y; a0.z += ev.z * wa.z; a0.w += ev.z * wa.w;
        a1.x += ev.z * wb.x; a1.y += ev.z * wb.y; a1.z += ev.z * wb.z; a1.w += ev.z * wb.w;
        wa = *(const float4*)(w1p + 3 * HH); wb = *(const float4*)(w1p + 3 * HH + 4);
        a0.x += ev.w * wa.x; a0.y += ev.w * wa.y; a0.z += ev.w * wa.z; a0.w += ev.w * wa.w;
        a1.x += ev.w * wb.x; a1.y += ev.w * wb.y; a1.z += ev.w * wb.z; a1.w += ev.w * wb.w;
      }
      *(float4*)(&sm.enc[t * ENC_STRIDE + ks])     = a0;
      *(float4*)(&sm.enc[t * ENC_STRIDE + ks + 4]) = a1;
    }
  }

  // Persistent per-thread weights: thread u -> gate g=u&3, unit m=u>>2, col=g*128+m.
  const int g = u & 3;
  const int m = u >> 2;
  const int col = g * HH + m;
  const float wk0 = Wk[col];
  const float wk1 = Wk[512 + col];
  const float bb  = bias[col];
  float wrreg[HH];                       // Wr column `col` resident in VGPRs
  #pragma unroll
  for (int k = 0; k < HH; ++k) wrreg[k] = Wr[k * 512 + col];
  float w2reg[32];                       // W2[g*32..g*32+31][m]
  #pragma unroll
  for (int j = 0; j < 32; ++j) w2reg[j] = W2[(g * 32 + j) * HH + m];
  float c = c0[b * HH + m];              // all 4 quad lanes carry identical c
  float ptr0 = 1.0f, ptr1 = 1.0f;

  __syncthreads();
  const float svr = sm.sv;
  const float C2 = 2.8853900817779268f;
  float* outb = out + (size_t)b * TT * TT;

  #pragma unroll 1
  for (int step = 0; step < TT; ++step) {
    // ---- A: z[col] = b + ptr@Wk + h@Wr (Wr from regs, h broadcast from LDS) ----
    float z = bb + ptr0 * wk0 + ptr1 * wk1;
    const float4* h4 = (const float4*)sm.h;
    #pragma unroll
    for (int k4 = 0; k4 < 32; ++k4) {
      float4 hv = h4[k4];
      z += hv.x * wrreg[4 * k4 + 0];
      z += hv.y * wrreg[4 * k4 + 1];
      z += hv.z * wrreg[4 * k4 + 2];
      z += hv.w * wrreg[4 * k4 + 3];
    }
    // quad exchange: every lane of the quad gets all 4 gate preactivations
    float za = __shfl_xor(z, 1);
    float zb = __shfl_xor(z, 2);
    float zc = __shfl_xor(za, 2);
    float zi = (g == 0) ? z  : (g == 1) ? za : (g == 2) ? zb : zc;
    float zf = (g == 0) ? za : (g == 1) ? z  : (g == 2) ? zc : zb;
    float zg = (g == 0) ? zb : (g == 1) ? zc : (g == 2) ? z  : za;
    float zo = (g == 0) ? zc : (g == 1) ? zb : (g == 2) ? za : z;
    float ig = fast_sigmoid(zi);
    float fg = fast_sigmoid(zf);
    float gg = fast_tanh(zg);
    float og = fast_sigmoid(zo);
    c = fg * c + ig * gg;
    float hn = og * fast_tanh(c);

    __syncthreads();                     // (alpha) all reads of old h complete
    if (g == 0) sm.h[m] = hn;
    __syncthreads();                     // (beta) new h visible

    // ---- C: uc2[k] = (h @ W2)[k] * 2log2e  (W2 from regs, quad-split over j) ----
    float part = 0.0f;
    const float4* h4b = (const float4*)(sm.h + g * 32);
    #pragma unroll
    for (int j4 = 0; j4 < 8; ++j4) {
      float4 hv = h4b[j4];
      part += hv.x * w2reg[4 * j4 + 0];
      part += hv.y * w2reg[4 * j4 + 1];
      part += hv.z * w2reg[4 * j4 + 2];
      part += hv.w * w2reg[4 * j4 + 3];
    }
    part += __shfl_xor(part, 1);
    part += __shfl_xor(part, 2);
    if (g == 0) sm.uc2[m] = part * C2;
    __syncthreads();                     // (gamma) uc2 visible

    // ---- D: scores[t] = sum(V) + sum_k (-2 V_k)/(1 + exp2((e+u)*2log2e)) ----
    const int t    = u >> 1;
    const int half = u & 1;
    const float4* e4  = (const float4*)(&sm.enc[t * ENC_STRIDE + half * 64]);
    const float4* uc4 = (const float4*)(sm.uc2 + half * 64);
    const float4* v4  = (const float4*)(sm.v2 + half * 64);
    float acc = 0.0f;
    #pragma unroll
    for (int c4 = 0; c4 < 16; ++c4) {
      float4 evv = e4[c4];
      float4 uv  = uc4[c4];
      float4 vv  = v4[c4];
      acc += vv.x * __builtin_amdgcn_rcpf(1.0f + __builtin_amdgcn_exp2f(evv.x * C2 + uv.x));
      acc += vv.y * __builtin_amdgcn_rcpf(1.0f + __builtin_amdgcn_exp2f(evv.y * C2 + uv.y));
      acc += vv.z * __builtin_amdgcn_rcpf(1.0f + __builtin_amdgcn_exp2f(evv.z * C2 + uv.z));
      acc += vv.w * __builtin_amdgcn_rcpf(1.0f + __builtin_amdgcn_exp2f(evv.w * C2 + uv.w));
    }
    acc += __shfl_xor(acc, 1);           // combine the two k-halves (adjacent lanes)
    float score = svr + acc;
    if (half == 0) outb[(size_t)step * TT + t] = score;   // raw score; softmax later

    // ---- argmax over t (first-max tie-break), broadcast ptr to all threads ----
    float bs = score; int bt = t;
    #pragma unroll
    for (int o = 1; o < 64; o <<= 1) {
      float s2 = __shfl_xor(bs, o);
      int   t2 = __shfl_xor(bt, o);
      if (s2 > bs || (s2 == bs && t2 < bt)) { bs = s2; bt = t2; }
    }
    if ((u & 63) == 0) { sm.red_s[u >> 6] = bs; sm.red_t[u >> 6] = bt; }
    __syncthreads();                     // (delta) wave partials visible
    float fbs = sm.red_s[0]; int fbt = sm.red_t[0];
    #pragma unroll
    for (int w = 1; w < 8; ++w) {
      float s2 = sm.red_s[w]; int t2 = sm.red_t[w];
      if (s2 > fbs || (s2 == fbs && t2 < fbt)) { fbs = s2; fbt = t2; }
    }
    ptr0 = sm.xloc[fbt * 2 + 0];
    ptr1 = sm.xloc[fbt * 2 + 1];
  }
}

// Row-wise softmax over the stored raw scores: 16384 rows of 256.
__global__ __launch_bounds__(256, 4)
void softmax_kernel(float* __restrict__ out)
{
  __shared__ float rmax[4];
  __shared__ float rsum[4];
  const int u = threadIdx.x;
  float* row = out + (size_t)blockIdx.x * 256;
  float v = row[u];
  float mx = v;
  #pragma unroll
  for (int o = 1; o < 64; o <<= 1) mx = fmaxf(mx, __shfl_xor(mx, o));
  if ((u & 63) == 0) rmax[u >> 6] = mx;
  __syncthreads();
  mx = fmaxf(fmaxf(rmax[0], rmax[1]), fmaxf(rmax[2], rmax[3]));
  float e = expf(v - mx);
  float s = e;
  #pragma unroll
  for (int o = 1; o < 64; o <<= 1) s += __shfl_xor(s, o);
  if ((u & 63) == 0) rsum[u >> 6] = s;
  __syncthreads();
  s = rsum[0] + rsum[1] + rsum[2] + rsum[3];
  row[u] = e / s;
}

extern "C" void kernel_launch(void* const* d_in, const int* in_sizes, int n_in,
                              void* d_out, int out_size, void* d_ws, size_t ws_size,
                              hipStream_t stream) {
  (void)in_sizes; (void)n_in; (void)d_ws; (void)ws_size; (void)out_size;
  const float* x    = (const float*)d_in[0];
  const float* enc  = (const float*)d_in[1];
  const float* h0   = (const float*)d_in[2];
  const float* c0   = (const float*)d_in[3];
  const float* W1   = (const float*)d_in[4];
  const float* W2   = (const float*)d_in[5];
  const float* V    = (const float*)d_in[6];
  const float* Wk   = (const float*)d_in[7];
  const float* Wr   = (const float*)d_in[8];
  const float* bias = (const float*)d_in[9];
  float* out = (float*)d_out;

  decoder_kernel<<<64, 512, 0, stream>>>(x, enc, h0, c0, W1, W2, V, Wk, Wr, bias, out);
  softmax_kernel<<<64 * 256, 256, 0, stream>>>(out);
}